// Round 15
// baseline (151.816 us; speedup 1.0000x reference)
//
#include <hip/hip_runtime.h>
#include <hip/hip_bf16.h>

typedef __attribute__((ext_vector_type(8))) short short8;
typedef __attribute__((ext_vector_type(4))) float f32x4;

#define MFMA16 __builtin_amdgcn_mfma_f32_16x16x32_bf16

__device__ inline unsigned short f2bf(float f) {
  __hip_bfloat16 h = __float2bfloat16(f);
  unsigned short u;
  __builtin_memcpy(&u, &h, 2);
  return u;
}

__device__ inline float bf2f(unsigned short u) {
  unsigned int x = ((unsigned int)u) << 16;
  float f;
  __builtin_memcpy(&f, &x, 4);
  return f;
}

__device__ inline void storeC(unsigned short* p, float v) { *p = f2bf(v); }
__device__ inline void storeC(float* p, float v) { *p = v; }

__device__ inline void gload16(const void* g, void* l) {
  __builtin_amdgcn_global_load_lds(
      (const __attribute__((address_space(1))) unsigned int*)g,
      (__attribute__((address_space(3))) unsigned int*)l,
      16, 0, 0);
}

// ---------------------------------------------------------------------------
// Fused weight prep (one launch, 1024 blocks) — unchanged from R14.
__global__ __launch_bounds__(256)
void prep_all(const float* __restrict__ Wq, const float* __restrict__ Wk,
              const float* __restrict__ Wv, const float* __restrict__ Wo,
              unsigned short* __restrict__ Wt, unsigned short* __restrict__ WoT) {
  __shared__ float t[64][65];
  const int bid = blockIdx.x;
  const int tid = threadIdx.x;
  if (bid < 256) {
    const int n0 = (bid & 7) * 64, d0 = (bid >> 3) * 64;
#pragma unroll
    for (int it = 0; it < 16; ++it) {
      const int idx = it * 256 + tid;
      const int dd = idx >> 6, nn = idx & 63;
      const float* p = Wq + (size_t)(d0 + dd) * 2048 + n0 + nn;
      t[dd][nn] = p[0] + p[512] + p[1024] + p[1536];
    }
    __syncthreads();
#pragma unroll
    for (int it = 0; it < 16; ++it) {
      const int idx = it * 256 + tid;
      const int nn = idx >> 6, dd = idx & 63;
      Wt[(size_t)(n0 + nn) * 2048 + d0 + dd] = f2bf(t[dd][nn]);
    }
    return;
  }
  const float* src;
  unsigned short* dst;
  int R, C, c0, r0;
  if (bid < 768) {
    const int b = bid - 256;
    const int z = b >> 8;
    const int bb = b & 255;
    src = z ? Wv : Wk;
    dst = Wt + (z ? 2097152 : 1048576);
    R = 2048; C = 512;
    c0 = (bb & 7) * 64; r0 = (bb >> 3) * 64;
  } else {
    const int b = bid - 768;
    src = Wo; dst = WoT;
    R = 512; C = 2048;
    c0 = (b & 31) * 64; r0 = (b >> 5) * 64;
  }
#pragma unroll
  for (int it = 0; it < 16; ++it) {
    const int idx = it * 256 + tid;
    const int r = idx >> 6, c = idx & 63;
    t[r][c] = src[(size_t)(r0 + r) * C + c0 + c];
  }
  __syncthreads();
#pragma unroll
  for (int it = 0; it < 16; ++it) {
    const int idx = it * 256 + tid;
    const int rr = idx >> 6, cc = idx & 63;
    dst[(size_t)(c0 + rr) * R + r0 + cc] = f2bf(t[cc][rr]);
  }
}

// Convert Q/K/V f32 -> bf16 contiguous [z][4096][2048]. grid(1024,3) x 256.
__global__ __launch_bounds__(256)
void conv_bf16(const float* __restrict__ Q, const float* __restrict__ K_,
               const float* __restrict__ V, unsigned short* __restrict__ dst) {
  const int z = blockIdx.y;
  const float* src = (z == 0) ? Q : (z == 1) ? K_ : V;
  unsigned short* d = dst + (size_t)z * 8388608;
  size_t i = ((size_t)blockIdx.x * 256 + threadIdx.x) * 8;
  const size_t stride = (size_t)gridDim.x * 256 * 8;
  for (; i < 8388608; i += stride) {
    const float4 v0 = *(const float4*)(src + i);
    const float4 v1 = *(const float4*)(src + i + 4);
    short8 o;
    o[0] = (short)f2bf(v0.x); o[1] = (short)f2bf(v0.y);
    o[2] = (short)f2bf(v0.z); o[3] = (short)f2bf(v0.w);
    o[4] = (short)f2bf(v1.x); o[5] = (short)f2bf(v1.y);
    o[6] = (short)f2bf(v1.z); o[7] = (short)f2bf(v1.w);
    *(short8*)(d + i) = o;
  }
}

// ---------------------------------------------------------------------------
// Tri-buffered counted-vmcnt GEMM: C[4096,N] = A[4096,K] * Bt[N,K]^T, bf16.
// BM=BN=128, BK=32, 4 waves (2m x 2n, 64x64 per wave, acc 4x4).
// LDS = 3 bufs x (A 8KB + B 8KB) = 48KB (~3 blocks/CU).
// Per step s: issue 4 gload_lds for step s+2 into buf (s+2)%3, then
// 8 ds_read_b128 + 16 MFMA from buf s%3, then vmcnt(4) (s+1's loads landed,
// s+2's stay in flight -> 2 steps of cover, never drain to 0 mid-loop),
// then ONE s_barrier, with sched_barrier(0) pinning every wait/barrier so
// the compiler cannot hoist LDS reads or stage issues across (R13's race).
// Pure-gload FIFO: no register-dependent VMEM in the loop, counts exact.
// XOR swizzle (r&3)<<4 within 64B rows via pre-swizzled global source.
template <typename CT>
__global__ __launch_bounds__(256, 2)
void gemm3t(const unsigned short* __restrict__ A,
            const unsigned short* __restrict__ Bt, CT* __restrict__ C,
            int K, int N, int ntile, size_t sA, size_t sB, size_t sC) {
  __shared__ char lds[49152];  // 3 x 16384 (A @+0, B @+8192)

  const int tid = threadIdx.x;
  const int lane = tid & 63;
  const int wv = tid >> 6;
  const int wm = (wv >> 1) << 6;
  const int wn = (wv & 1) << 6;
  const int l15 = lane & 15;
  const int l4 = lane >> 4;

  // XCD-aware bijective swizzle (grid % 8 == 0), n-tiles innermost.
  const int nwg = gridDim.x;
  const int bid = blockIdx.x;
  const int job = (bid & 7) * (nwg >> 3) + (bid >> 3);
  const int z = job / (32 * ntile);
  const int rem = job - z * 32 * ntile;
  const int m0 = (rem / ntile) << 7;
  const int n0 = (rem % ntile) << 7;

  const unsigned short* Az = A + sA * (size_t)z;
  const unsigned short* Bz = Bt + sB * (size_t)z;

  const f32x4 zero = {0.f, 0.f, 0.f, 0.f};
  f32x4 acc[4][4];
#pragma unroll
  for (int i = 0; i < 4; ++i)
#pragma unroll
    for (int j = 0; j < 4; ++j) acc[i][j] = zero;

  // stage one K-step (BK=32): A 8KB (2 gloads/thread) + B 8KB (2 gloads)
  auto stage = [&](int buf, int k0) {
#pragma unroll
    for (int i = 0; i < 2; ++i) {
      const int flat = i * 4096 + tid * 16;
      const int r = flat >> 6;                       // 0..127
      const int colb = (flat & 63) ^ ((r & 3) << 4); // pre-swizzled source
      gload16((const char*)(Az + (size_t)(m0 + r) * K + k0) + colb,
              lds + buf * 16384 + flat);
    }
#pragma unroll
    for (int i = 0; i < 2; ++i) {
      const int flat = i * 4096 + tid * 16;
      const int r = flat >> 6;
      const int colb = (flat & 63) ^ ((r & 3) << 4);
      gload16((const char*)(Bz + (size_t)(n0 + r) * K + k0) + colb,
              lds + buf * 16384 + 8192 + flat);
    }
  };

  const int NS = K >> 5;

  // prologue: buf0 <- step0, buf1 <- step1; wait step0 (4 of 8 outstanding)
  stage(0, 0);
  stage(1, 32);
  asm volatile("s_waitcnt vmcnt(4)" ::: "memory");
  __builtin_amdgcn_sched_barrier(0);
  __builtin_amdgcn_s_barrier();
  __builtin_amdgcn_sched_barrier(0);

  int b = 0;
  for (int s = 0; s < NS; ++s) {
    const int b2 = (b + 2 >= 3) ? (b - 1) : (b + 2);
    if (s + 2 < NS) stage(b2, (s + 2) << 5);
    const char* L = lds + b * 16384;
    short8 a[4], bf[4];
#pragma unroll
    for (int i = 0; i < 4; ++i) {
      const int r = wm + i * 16 + l15;
      a[i] = *(const short8*)(L + r * 64 + ((l4 << 4) ^ ((r & 3) << 4)));
    }
#pragma unroll
    for (int j = 0; j < 4; ++j) {
      const int r = wn + j * 16 + l15;
      bf[j] = *(const short8*)(L + 8192 + r * 64 + ((l4 << 4) ^ ((r & 3) << 4)));
    }
    __builtin_amdgcn_s_setprio(1);
#pragma unroll
    for (int i = 0; i < 4; ++i)
#pragma unroll
      for (int j = 0; j < 4; ++j)
        acc[i][j] = MFMA16(a[i], bf[j], acc[i][j], 0, 0, 0);
    __builtin_amdgcn_s_setprio(0);
    if (s + 1 < NS) {
      if (s + 2 < NS) {
        asm volatile("s_waitcnt vmcnt(4)" ::: "memory");
      } else {
        asm volatile("s_waitcnt vmcnt(0)" ::: "memory");
      }
      __builtin_amdgcn_sched_barrier(0);
      __builtin_amdgcn_s_barrier();
      __builtin_amdgcn_sched_barrier(0);
    }
    b = (b + 1 == 3) ? 0 : b + 1;
  }

  CT* Cz = C + sC * (size_t)z;
#pragma unroll
  for (int i = 0; i < 4; ++i) {
    const int row0 = m0 + wm + i * 16 + (l4 << 2);
#pragma unroll
    for (int j = 0; j < 4; ++j) {
      const int col = n0 + wn + j * 16 + l15;
#pragma unroll
      for (int r = 0; r < 4; ++r)
        storeC(&Cz[(size_t)(row0 + r) * N + col], acc[i][j][r]);
    }
  }
}

// ---------------------------------------------------------------------------
// Re-layout q,k into fragment-major packed form (pure copy):
//   qpack/kpack[bh][blk16][kk][lane64][e8] =
//     X[(bh>>2)*2048 + blk*16 + (lane&15)][(bh&3)*128 + kk*32 + (lane>>4)*8+e]
__global__ __launch_bounds__(256)
void qkv_pack(const unsigned short* __restrict__ qh,
              const unsigned short* __restrict__ kh,
              unsigned short* __restrict__ qpack,
              unsigned short* __restrict__ kpack) {
  const int idx = blockIdx.x * 256 + threadIdx.x;
  const int lane = idx & 63;
  const int kk = (idx >> 6) & 3;
  const int qb = (idx >> 8) & 127;
  const int bh = idx >> 15;
  const int row = (bh >> 2) * 2048 + qb * 16 + (lane & 15);
  const int col = (bh & 3) * 128 + kk * 32 + (lane >> 4) * 8;
  const size_t off = (size_t)row * 512 + col;
  *(short8*)(qpack + (size_t)idx * 8) = *(const short8*)(qh + off);
  *(short8*)(kpack + (size_t)idx * 8) = *(const short8*)(kh + off);
}

// Re-layout v into packed PV B-operand form (LDS-staged transpose):
//   vpack[bh][kvb32][d8][lane64][e8] = V[b][kvb32*32 + (lane>>4)*8 + e]
//                                       [h*128 + d8*16 + (lane&15)]
__global__ __launch_bounds__(256)
void vpack_k(const unsigned short* __restrict__ vh,
             unsigned short* __restrict__ vpack) {
  __shared__ unsigned short t[32][132];
  const int kvb = blockIdx.x;
  const int bh = blockIdx.y;
  const int brow = (bh >> 2) * 2048;
  const int h = bh & 3;
  const int tid = threadIdx.x;
#pragma unroll
  for (int it = 0; it < 2; ++it) {
    const int idx = it * 256 + tid;
    const int r = idx >> 4;
    const int c8 = (idx & 15) << 3;
    const size_t off = (size_t)(brow + kvb * 32 + r) * 512 + h * 128 + c8;
    *(short8*)&t[r][c8] = *(const short8*)(vh + off);
  }
  __syncthreads();
#pragma unroll
  for (int it = 0; it < 2; ++it) {
    const int idx = it * 256 + tid;
    const int d8 = idx >> 6;
    const int lane = idx & 63;
    const int l15 = lane & 15;
    const int l4 = lane >> 4;
    short8 o;
#pragma unroll
    for (int e = 0; e < 8; ++e) o[e] = (short)t[l4 * 8 + e][d8 * 16 + l15];
    *(short8*)(vpack + ((((size_t)bh * 64 + kvb) * 8 + d8) * 64 + lane) * 8) = o;
  }
}

// ---------------------------------------------------------------------------
// Split-KV flash attention v5 (unchanged from R14): packed operands,
// tile-level prefetch, static-max softmax, barrier-free, XCD-bh affinity.
__global__ __launch_bounds__(128, 1)
void attn_split(const unsigned short* __restrict__ qpack,
                const unsigned short* __restrict__ kpack,
                const unsigned short* __restrict__ vpack,
                unsigned short* __restrict__ Oh,
                unsigned short* __restrict__ pO,
                float* __restrict__ pml) {
  __shared__ unsigned short P_lds[2][32][36];
  const int tid = threadIdx.x;
  const int lane = tid & 63;
  const int wave = tid >> 6;
  const int l15 = lane & 15;
  const int l4 = lane >> 4;
  const int bh = blockIdx.x & 7;
  const int jid = 143 - (int)(blockIdx.x >> 3);
  const int brow = (bh >> 2) * 2048;
  const int h = bh & 3;

  int j = jid, g = 0;
  while (j >= 2 * (g + 1) * (g + 2)) ++g;
  const int rem = j - 2 * g * (g + 1);
  const int r_ = rem / (g + 1);
  const int c_ = rem - r_ * (g + 1);
  const int qt = 4 * g + r_;
  const int k_begin = c_ << 8;
  const int k_end = (c_ == g) ? (qt + 1) * 64 : ((c_ + 1) << 8);
  const int qrow_w = qt * 64 + wave * 32;
  const float SCALE2 = 0.127517424f;  // log2(e)/sqrt(128)

  short8 qf[2][4];
#pragma unroll
  for (int m = 0; m < 2; ++m)
#pragma unroll
    for (int kk = 0; kk < 4; ++kk)
      qf[m][kk] = *(const short8*)(qpack +
          ((((size_t)bh * 128 + (qrow_w >> 4) + m) * 4 + kk) * 64 + lane) * 8);

  short8 oneb;
#pragma unroll
  for (int e = 0; e < 8; ++e) oneb[e] = (short)0x3F80;

  const f32x4 zero = {0.f, 0.f, 0.f, 0.f};
  f32x4 o_acc[2][8];
  f32x4 l_acc[2];
#pragma unroll
  for (int m = 0; m < 2; ++m) {
    l_acc[m] = zero;
#pragma unroll
    for (int i = 0; i < 8; ++i) o_acc[m][i] = zero;
  }

  const int nt = (k_end - k_begin) >> 5;
  int ntv = ((qrow_w + 31 - k_begin) >> 5) + 1;
  if (ntv > nt) ntv = nt;

  auto loadK = [&](short8 (&kf)[2][4], int t) {
    const int kvb = (k_begin >> 4) + t * 2;
#pragma unroll
    for (int n = 0; n < 2; ++n)
#pragma unroll
      for (int kk = 0; kk < 4; ++kk)
        kf[n][kk] = *(const short8*)(kpack +
            ((((size_t)bh * 128 + kvb + n) * 4 + kk) * 64 + lane) * 8);
  };
  auto loadV = [&](short8 (&vb)[8], int t) {
    const int kvb32 = (k_begin >> 5) + t;
#pragma unroll
    for (int d8 = 0; d8 < 8; ++d8)
      vb[d8] = *(const short8*)(vpack +
          ((((size_t)bh * 64 + kvb32) * 8 + d8) * 64 + lane) * 8);
  };
  auto compute = [&](int t, short8 (&kf)[2][4], short8 (&vb)[8]) {
    const int kbase = k_begin + t * 32;
    f32x4 sa[2][2];
    sa[0][0] = zero; sa[0][1] = zero; sa[1][0] = zero; sa[1][1] = zero;
#pragma unroll
    for (int n = 0; n < 2; ++n)
#pragma unroll
      for (int kk = 0; kk < 4; ++kk) {
        sa[0][n] = MFMA16(qf[0][kk], kf[n][kk], sa[0][n], 0, 0, 0);
        sa[1][n] = MFMA16(qf[1][kk], kf[n][kk], sa[1][n], 0, 0, 0);
      }
    const bool need_mask = (kbase + 31 > qrow_w);
    float p[2][2][4];
#pragma unroll
    for (int m = 0; m < 2; ++m)
#pragma unroll
      for (int n = 0; n < 2; ++n)
#pragma unroll
        for (int r = 0; r < 4; ++r) {
          const float v = exp2f(sa[m][n][r] * SCALE2 - 24.f);
          bool msk = false;
          if (need_mask) {
            const int kc = kbase + n * 16 + l15;
            const int qr = qrow_w + m * 16 + (l4 << 2) + r;
            msk = (kc > qr);
          }
          p[m][n][r] = msk ? 0.f : v;
        }
#pragma unroll
    for (int m = 0; m < 2; ++m)
#pragma unroll
      for (int n = 0; n < 2; ++n)
#pragma unroll
        for (int r = 0; r < 4; ++r)
          P_lds[wave][m * 16 + (l4 << 2) + r][n * 16 + l15] = f2bf(p[m][n][r]);
    short8 pa[2];
#pragma unroll
    for (int m = 0; m < 2; ++m)
      pa[m] = *(const short8*)((const char*)&P_lds[wave][0][0] +
                               (m * 16 + l15) * 72 + (l4 << 4));
    l_acc[0] = MFMA16(pa[0], oneb, l_acc[0], 0, 0, 0);
    l_acc[1] = MFMA16(pa[1], oneb, l_acc[1], 0, 0, 0);
#pragma unroll
    for (int d8 = 0; d8 < 8; ++d8) {
      o_acc[0][d8] = MFMA16(pa[0], vb[d8], o_acc[0][d8], 0, 0, 0);
      o_acc[1][d8] = MFMA16(pa[1], vb[d8], o_acc[1][d8], 0, 0, 0);
    }
  };

  short8 kfA[2][4], vbA[8], kfB[2][4], vbB[8];
  loadK(kfA, 0);
  loadV(vbA, 0);
  for (int t = 0; t < ntv; t += 2) {
    if (t + 1 < ntv) { loadK(kfB, t + 1); loadV(vbB, t + 1); }
    compute(t, kfA, vbA);
    if (t + 1 < ntv) {
      if (t + 2 < ntv) { loadK(kfA, t + 2); loadV(vbA, t + 2); }
      compute(t + 1, kfB, vbB);
    }
  }

  if (g == 0) {
#pragma unroll
    for (int m = 0; m < 2; ++m)
#pragma unroll
      for (int d8 = 0; d8 < 8; ++d8)
#pragma unroll
        for (int r = 0; r < 4; ++r) {
          const int row = brow + qrow_w + m * 16 + (l4 << 2) + r;
          Oh[(size_t)row * 512 + h * 128 + d8 * 16 + l15] =
              f2bf(o_acc[m][d8][r] / l_acc[m][r]);
        }
  } else {
    const int slot = bh * 144 + jid;
    unsigned short* po = pO + (size_t)slot * 64 * 128;
#pragma unroll
    for (int m = 0; m < 2; ++m)
#pragma unroll
      for (int d8 = 0; d8 < 8; ++d8)
#pragma unroll
        for (int r = 0; r < 4; ++r) {
          const int row = wave * 32 + m * 16 + (l4 << 2) + r;
          po[row * 128 + d8 * 16 + l15] = f2bf(o_acc[m][d8][r]);
        }
    if (l15 == 0) {
#pragma unroll
      for (int m = 0; m < 2; ++m)
#pragma unroll
        for (int r = 0; r < 4; ++r) {
          const int row = wave * 32 + m * 16 + (l4 << 2) + r;
          pml[((size_t)slot * 64 + row) * 2 + 0] = 0.f;
          pml[((size_t)slot * 64 + row) * 2 + 1] = l_acc[m][r];
        }
    }
  }
}

// Combine partials for qt >= 4 (static max -> all weights 1).
__global__ __launch_bounds__(256)
void attn_combine(const unsigned short* __restrict__ pO,
                  const float* __restrict__ pml,
                  unsigned short* __restrict__ Oh) {
  const int bh = blockIdx.y;
  const int qt = 4 + blockIdx.x;
  const int g = qt >> 2;
  const int nch = g + 1;
  const int base = 2 * g * (g + 1) + (qt & 3) * (g + 1);
  const int slot0 = bh * 144 + base;
  const int brow = (bh >> 2) * 2048;
  const int h = bh & 3;
#pragma unroll
  for (int u = 0; u < 4; ++u) {
    const int unit = u * 256 + threadIdx.x;
    const int row = unit >> 4;
    const int c8 = (unit & 15) << 3;
    float M = -1e30f;
    for (int c = 0; c < nch; ++c)
      M = fmaxf(M, pml[((size_t)(slot0 + c) * 64 + row) * 2]);
    float L = 0.f;
    float acc[8] = {0.f, 0.f, 0.f, 0.f, 0.f, 0.f, 0.f, 0.f};
    for (int c = 0; c < nch; ++c) {
      const float mc = pml[((size_t)(slot0 + c) * 64 + row) * 2];
      const float lc = pml[((size_t)(slot0 + c) * 64 + row) * 2 + 1];
      const float w = exp2f(mc - M);
      L += w * lc;
      const short8 ov =
          *(const short8*)(pO + ((size_t)(slot0 + c) * 64 + row) * 128 + c8);
#pragma unroll
      for (int e = 0; e < 8; ++e) acc[e] += w * bf2f((unsigned short)ov[e]);
    }
    const float inv = 1.f / L;
    short8 o;
#pragma unroll
    for (int e = 0; e < 8; ++e) o[e] = (short)f2bf(acc[e] * inv);
    *(short8*)(Oh + (size_t)(brow + qt * 64 + row) * 512 + h * 128 + c8) = o;
  }
}

// ---------------------------------------------------------------------------
extern "C" void kernel_launch(void* const* d_in, const int* in_sizes, int n_in,
                              void* d_out, int out_size, void* d_ws, size_t ws_size,
                              hipStream_t stream) {
  const float* Q  = (const float*)d_in[0];
  const float* K_ = (const float*)d_in[1];
  const float* V  = (const float*)d_in[2];
  const float* Wq = (const float*)d_in[3];
  const float* Wk = (const float*)d_in[4];
  const float* Wv = (const float*)d_in[5];
  const float* Wo = (const float*)d_in[6];
  float* out = (float*)d_out;

  // ws layout (bytes), total <= 48824320:
  //   0         : Wt    3 x [512][2048] bf16      [0, 6291456)
  //   6291456   : WoT   [2048][512] bf16          [6291456, 8388608)
  //   8388608   : Abf   [3][4096][2048] bf16      [8388608, 33554432)  (dies after QKV gemm)
  //   33554432  : qh/kh/vh 3 x [4096][512] bf16   [33554432, 46137344) (die after packs)
  //   -- Abf region reuse after QKV gemm: --
  //   8388608   : qpack (4.19 MB); 12582912: kpack; 16777216: vpack
  //   20971520  : Oh [4096][512] bf16
  //   25165824  : pO [1152][64][128] bf16 (ends 44040192; over dead qh/kh/vh)
  //   48234496  : pml [1152][64][2] f32 (ends 48824320)
  char* ws = (char*)d_ws;
  unsigned short* Wt    = (unsigned short*)ws;
  unsigned short* WoT   = (unsigned short*)(ws + 6291456);
  unsigned short* Abf   = (unsigned short*)(ws + 8388608);
  unsigned short* qh    = (unsigned short*)(ws + 33554432);
  unsigned short* kh    = (unsigned short*)(ws + 37748736);
  unsigned short* vh    = (unsigned short*)(ws + 41943040);
  unsigned short* qpack = (unsigned short*)(ws + 8388608);
  unsigned short* kpack = (unsigned short*)(ws + 12582912);
  unsigned short* vpack = (unsigned short*)(ws + 16777216);
  unsigned short* Oh    = (unsigned short*)(ws + 20971520);
  unsigned short* pO    = (unsigned short*)(ws + 25165824);
  float*          pml   = (float*)(ws + 48234496);

  // weight prep + A convert
  prep_all<<<1024, 256, 0, stream>>>(Wq, Wk, Wv, Wo, Wt, WoT);
  conv_bf16<<<dim3(1024, 3), 256, 0, stream>>>(Q, K_, V, Abf);

  // QKV projections: tri-buffer counted-vmcnt GEMM, 32m x 4n x 3z = 384 blocks
  gemm3t<unsigned short><<<384, 256, 0, stream>>>(
      Abf, Wt, qh, /*K=*/2048, /*N=*/512, /*ntile=*/4,
      /*sA=*/8388608, /*sB=*/1048576, /*sC=*/2097152);

  // fragment re-pack (pure relayout)
  qkv_pack<<<1024, 256, 0, stream>>>(qh, kh, qpack, kpack);
  vpack_k<<<dim3(64, 8), 256, 0, stream>>>(vh, vpack);

  // split-KV causal attention + combine
  attn_split<<<1152, 128, 0, stream>>>(qpack, kpack, vpack, Oh, pO, pml);
  attn_combine<<<dim3(28, 8), 256, 0, stream>>>(pO, pml, Oh);

  // output projection: 32m x 16n = 512 blocks, K=512
  gemm3t<float><<<512, 256, 0, stream>>>(
      Oh, WoT, out, /*K=*/512, /*N=*/2048, /*ntile=*/16,
      /*sA=*/0, /*sB=*/0, /*sC=*/0);
}

// Round 16
// 128.942 us; speedup vs baseline: 1.1774x; 1.1774x over previous
//
#include <hip/hip_runtime.h>
#include <hip/hip_bf16.h>

typedef __attribute__((ext_vector_type(8))) short short8;
typedef __attribute__((ext_vector_type(4))) float f32x4;

#define MFMA16 __builtin_amdgcn_mfma_f32_16x16x32_bf16

__device__ inline unsigned short f2bf(float f) {
  __hip_bfloat16 h = __float2bfloat16(f);
  unsigned short u;
  __builtin_memcpy(&u, &h, 2);
  return u;
}

__device__ inline float bf2f(unsigned short u) {
  unsigned int x = ((unsigned int)u) << 16;
  float f;
  __builtin_memcpy(&f, &x, 4);
  return f;
}

__device__ inline void storeC(unsigned short* p, float v) { *p = f2bf(v); }
__device__ inline void storeC(float* p, float v) { *p = v; }

__device__ inline void gload16(const void* g, void* l) {
  __builtin_amdgcn_global_load_lds(
      (const __attribute__((address_space(1))) unsigned int*)g,
      (__attribute__((address_space(3))) unsigned int*)l,
      16, 0, 0);
}

// ---------------------------------------------------------------------------
// Fused weight prep (one launch, 1024 blocks):
//   bid [0,256)    : wqsum  dst[n][d] = sum_g Wq[d][n+g*512]  (512x2048 out)
//   bid [256,512)  : Wk^T -> Wt+1048576   (2048x512 -> 512x2048)
//   bid [512,768)  : Wv^T -> Wt+2097152
//   bid [768,1024) : Wo^T -> WoT          (512x2048 -> 2048x512)
__global__ __launch_bounds__(256)
void prep_all(const float* __restrict__ Wq, const float* __restrict__ Wk,
              const float* __restrict__ Wv, const float* __restrict__ Wo,
              unsigned short* __restrict__ Wt, unsigned short* __restrict__ WoT) {
  __shared__ float t[64][65];
  const int bid = blockIdx.x;
  const int tid = threadIdx.x;
  if (bid < 256) {
    const int n0 = (bid & 7) * 64, d0 = (bid >> 3) * 64;
#pragma unroll
    for (int it = 0; it < 16; ++it) {
      const int idx = it * 256 + tid;
      const int dd = idx >> 6, nn = idx & 63;
      const float* p = Wq + (size_t)(d0 + dd) * 2048 + n0 + nn;
      t[dd][nn] = p[0] + p[512] + p[1024] + p[1536];
    }
    __syncthreads();
#pragma unroll
    for (int it = 0; it < 16; ++it) {
      const int idx = it * 256 + tid;
      const int nn = idx >> 6, dd = idx & 63;
      Wt[(size_t)(n0 + nn) * 2048 + d0 + dd] = f2bf(t[dd][nn]);
    }
    return;
  }
  const float* src;
  unsigned short* dst;
  int R, C, c0, r0;
  if (bid < 768) {
    const int b = bid - 256;
    const int z = b >> 8;              // 0: Wk, 1: Wv
    const int bb = b & 255;
    src = z ? Wv : Wk;
    dst = Wt + (z ? 2097152 : 1048576);
    R = 2048; C = 512;
    c0 = (bb & 7) * 64; r0 = (bb >> 3) * 64;
  } else {
    const int b = bid - 768;
    src = Wo; dst = WoT;
    R = 512; C = 2048;
    c0 = (b & 31) * 64; r0 = (b >> 5) * 64;
  }
#pragma unroll
  for (int it = 0; it < 16; ++it) {
    const int idx = it * 256 + tid;
    const int r = idx >> 6, c = idx & 63;
    t[r][c] = src[(size_t)(r0 + r) * C + c0 + c];
  }
  __syncthreads();
#pragma unroll
  for (int it = 0; it < 16; ++it) {
    const int idx = it * 256 + tid;
    const int rr = idx >> 6, cc = idx & 63;
    dst[(size_t)(c0 + rr) * R + r0 + cc] = f2bf(t[cc][rr]);
  }
}

// ---------------------------------------------------------------------------
// GEMM C[M,N] = A[M,K] * Bt[N,K]^T.  128x128 tile, BK=64, 4 waves, T2 swizzle,
// KS split-K, XCD swizzle, cross-barrier prefetch (stable since R8).
template <bool AF32, typename CT, int KS>
__global__ __launch_bounds__(256)
void gemm_bt(const void* A0, const void* A1, const void* A2,
             const unsigned short* __restrict__ Bt, CT* __restrict__ C,
             int K, int N, size_t sB, size_t sC) {
  __shared__ unsigned short As[AF32 ? 1 : 2][128 * 64];
  __shared__ unsigned short Bs[2][128 * 64];

  const int tid = threadIdx.x;
  const int lane = tid & 63;
  const int wv = tid >> 6;
  const int wm = (wv >> 1) << 6;
  const int wn = (wv & 1) << 6;
  const int l15 = lane & 15;
  const int l4 = lane >> 4;
  const int lsw = (l15 & 7) << 4;

  const int nwg = gridDim.x;
  const int bid = blockIdx.x;
  const int job = (bid & 7) * (nwg >> 3) + (bid >> 3);
  const int ntile = N >> 7;
  const int per_ks = nwg / KS;
  const int ks = (KS > 1) ? (job / per_ks) : 0;
  const int jj = job - ks * per_ks;
  const int z = jj / (32 * ntile);
  const int rem = jj - z * 32 * ntile;
  const int m0 = (rem / ntile) << 7;
  const int n0 = (rem % ntile) << 7;
  const int kbeg = ks * (K / KS);
  const int kend = kbeg + K / KS;

  const void* Az = (z == 0) ? A0 : (z == 1) ? A1 : A2;
  const unsigned short* Ab = (const unsigned short*)Az;
  const float* Af = (const float*)Az;
  const unsigned short* Bz = Bt + sB * (size_t)z;

  const f32x4 zero = {0.f, 0.f, 0.f, 0.f};
  f32x4 acc[4][4];
#pragma unroll
  for (int i = 0; i < 4; ++i)
#pragma unroll
    for (int j = 0; j < 4; ++j) acc[i][j] = zero;

  const int srow = tid >> 3;
  const int scol = (tid & 7) << 3;
  const int scolsw = scol ^ ((srow & 7) << 3);

  float4 ar[8];

  auto issueB = [&](int buf, int k0) {
#pragma unroll
    for (int s = 0; s < 4; ++s) {
      const unsigned short* bsrc =
          Bz + (size_t)(n0 + srow + s * 32) * K + k0 + scolsw;
      gload16(bsrc, (char*)&Bs[buf][0] + tid * 16 + s * 4096);
    }
  };
  auto issueA16 = [&](int buf, int k0) {
#pragma unroll
    for (int s = 0; s < 4; ++s) {
      const unsigned short* asrc =
          Ab + (size_t)(m0 + srow + s * 32) * K + k0 + scolsw;
      gload16(asrc, (char*)&As[buf][0] + tid * 16 + s * 4096);
    }
  };
  auto loadA = [&](int k0) {
#pragma unroll
    for (int s = 0; s < 4; ++s) {
      const float* asrc = Af + (size_t)(m0 + srow + s * 32) * K + k0 + scol;
      ar[2 * s] = *(const float4*)(asrc);
      ar[2 * s + 1] = *(const float4*)(asrc + 4);
    }
  };
  auto writeA = [&]() {
#pragma unroll
    for (int s = 0; s < 4; ++s) {
      short8 o;
      o[0] = (short)f2bf(ar[2 * s].x); o[1] = (short)f2bf(ar[2 * s].y);
      o[2] = (short)f2bf(ar[2 * s].z); o[3] = (short)f2bf(ar[2 * s].w);
      o[4] = (short)f2bf(ar[2 * s + 1].x); o[5] = (short)f2bf(ar[2 * s + 1].y);
      o[6] = (short)f2bf(ar[2 * s + 1].z); o[7] = (short)f2bf(ar[2 * s + 1].w);
      *(short8*)((char*)&As[0][0] + (srow + s * 32) * 128 + scolsw * 2) = o;
    }
  };

  if constexpr (AF32) loadA(kbeg); else issueA16(0, kbeg);
  issueB(0, kbeg);

  int cur = 0;
  for (int k0 = kbeg; k0 < kend; k0 += 64) {
    const bool more = (k0 + 64 < kend);
    asm volatile("s_waitcnt vmcnt(0)" ::: "memory");
    if constexpr (AF32) {
      writeA();
      if (more) { issueB(cur ^ 1, k0 + 64); loadA(k0 + 64); }
      asm volatile("s_waitcnt lgkmcnt(0)" ::: "memory");
    } else {
      if (more) { issueA16(cur ^ 1, k0 + 64); issueB(cur ^ 1, k0 + 64); }
    }
    __builtin_amdgcn_s_barrier();
    const unsigned short* as = AF32 ? &As[0][0] : &As[cur][0];
#pragma unroll
    for (int kk = 0; kk < 2; ++kk) {
      const int kb = (kk * 64 + (l4 << 4)) ^ lsw;
      short8 a[4], b[4];
#pragma unroll
      for (int i = 0; i < 4; ++i)
        a[i] = *(const short8*)((const char*)as + (wm + i * 16 + l15) * 128 + kb);
#pragma unroll
      for (int j = 0; j < 4; ++j)
        b[j] = *(const short8*)((const char*)&Bs[cur][0] +
                                (wn + j * 16 + l15) * 128 + kb);
#pragma unroll
      for (int i = 0; i < 4; ++i)
#pragma unroll
        for (int j = 0; j < 4; ++j)
          acc[i][j] = MFMA16(a[i], b[j], acc[i][j], 0, 0, 0);
    }
    __builtin_amdgcn_s_barrier();
    cur ^= 1;
  }

  CT* Cz = C + sC * (size_t)(ks * 3 + z);
#pragma unroll
  for (int i = 0; i < 4; ++i) {
    const int row0 = m0 + wm + i * 16 + (l4 << 2);
#pragma unroll
    for (int j = 0; j < 4; ++j) {
      const int col = n0 + wn + j * 16 + l15;
#pragma unroll
      for (int r = 0; r < 4; ++r)
        storeC(&Cz[(size_t)(row0 + r) * N + col], acc[i][j][r]);
    }
  }
}

// ---------------------------------------------------------------------------
// Combine split-K partials for q,k AND emit fragment-major packed layouts:
//   qpack/kpack[bh][blk16][kk][lane64][e8]:
//     value = X[(bh>>2)*2048 + blk*16 + (lane&15)][(bh&3)*128 + kk*32 +
//              (lane>>4)*8 + e]
__global__ __launch_bounds__(256)
void qkv_pack(const unsigned short* __restrict__ pC,
              unsigned short* __restrict__ qpack,
              unsigned short* __restrict__ kpack) {
  const size_t SLOTE = 6291456;  // elems per ks slot
  const int idx = blockIdx.x * 256 + threadIdx.x;  // [bh][qb][kk][lane]
  const int lane = idx & 63;
  const int kk = (idx >> 6) & 3;
  const int qb = (idx >> 8) & 127;
  const int bh = idx >> 15;
  const int row = (bh >> 2) * 2048 + qb * 16 + (lane & 15);
  const int col = (bh & 3) * 128 + kk * 32 + (lane >> 4) * 8;
  const size_t off = (size_t)row * 512 + col;
  {
    const short8 a = *(const short8*)(pC + off);
    const short8 b = *(const short8*)(pC + SLOTE + off);
    short8 o;
#pragma unroll
    for (int e = 0; e < 8; ++e)
      o[e] = (short)f2bf(bf2f((unsigned short)a[e]) + bf2f((unsigned short)b[e]));
    *(short8*)(qpack + (size_t)idx * 8) = o;
  }
  {
    const short8 a = *(const short8*)(pC + 2097152 + off);
    const short8 b = *(const short8*)(pC + SLOTE + 2097152 + off);
    short8 o;
#pragma unroll
    for (int e = 0; e < 8; ++e)
      o[e] = (short)f2bf(bf2f((unsigned short)a[e]) + bf2f((unsigned short)b[e]));
    *(short8*)(kpack + (size_t)idx * 8) = o;
  }
}

// Combine split-K V partials and emit packed PV B-operand layout:
//   vpack[bh][kvb32][d8][lane64][e8] = V[b][kvb32*32 + (lane>>4)*8 + e]
//                                       [h*128 + d8*16 + (lane&15)]
__global__ __launch_bounds__(256)
void vpack_k(const unsigned short* __restrict__ pC,
             unsigned short* __restrict__ vpack) {
  __shared__ unsigned short t[32][132];
  const int kvb = blockIdx.x;
  const int bh = blockIdx.y;
  const int brow = (bh >> 2) * 2048;
  const int h = bh & 3;
  const int tid = threadIdx.x;
  const unsigned short* v0 = pC + 4194304;            // ks=0, z=2 slice
  const unsigned short* v1 = pC + 6291456 + 4194304;  // ks=1, z=2 slice
#pragma unroll
  for (int it = 0; it < 2; ++it) {
    const int idx = it * 256 + tid;
    const int r = idx >> 4;
    const int c8 = (idx & 15) << 3;
    const size_t off = (size_t)(brow + kvb * 32 + r) * 512 + h * 128 + c8;
    const short8 xa = *(const short8*)(v0 + off);
    const short8 xb = *(const short8*)(v1 + off);
    short8 o;
#pragma unroll
    for (int e = 0; e < 8; ++e)
      o[e] = (short)f2bf(bf2f((unsigned short)xa[e]) + bf2f((unsigned short)xb[e]));
    *(short8*)&t[r][c8] = o;
  }
  __syncthreads();
#pragma unroll
  for (int it = 0; it < 2; ++it) {
    const int idx = it * 256 + tid;
    const int d8 = idx >> 6;
    const int lane = idx & 63;
    const int l15 = lane & 15;
    const int l4 = lane >> 4;
    short8 o;
#pragma unroll
    for (int e = 0; e < 8; ++e) o[e] = (short)t[l4 * 8 + e][d8 * 16 + l15];
    *(short8*)(vpack + ((((size_t)bh * 64 + kvb) * 8 + d8) * 64 + lane) * 8) = o;
  }
}

// ---------------------------------------------------------------------------
// Split-KV flash attention v5: packed operands (1KB contiguous wave-loads),
// tile-level prefetch (unroll-2, named reg sets), static-max softmax
// p = exp2(s*log2e/sqrt(128) - 24), barrier-free, XCD-bh affinity,
// longest-job-first, l row-sum via MFMA(pa, ones).
__global__ __launch_bounds__(128, 1)
void attn_split(const unsigned short* __restrict__ qpack,
                const unsigned short* __restrict__ kpack,
                const unsigned short* __restrict__ vpack,
                unsigned short* __restrict__ Oh,
                unsigned short* __restrict__ pO,
                float* __restrict__ pml) {
  __shared__ unsigned short P_lds[2][32][36];
  const int tid = threadIdx.x;
  const int lane = tid & 63;
  const int wave = tid >> 6;
  const int l15 = lane & 15;
  const int l4 = lane >> 4;
  const int bh = blockIdx.x & 7;
  const int jid = 143 - (int)(blockIdx.x >> 3);
  const int brow = (bh >> 2) * 2048;
  const int h = bh & 3;

  int j = jid, g = 0;
  while (j >= 2 * (g + 1) * (g + 2)) ++g;
  const int rem = j - 2 * g * (g + 1);
  const int r_ = rem / (g + 1);
  const int c_ = rem - r_ * (g + 1);
  const int qt = 4 * g + r_;
  const int k_begin = c_ << 8;
  const int k_end = (c_ == g) ? (qt + 1) * 64 : ((c_ + 1) << 8);
  const int qrow_w = qt * 64 + wave * 32;
  const float SCALE2 = 0.127517424f;  // log2(e)/sqrt(128)

  short8 qf[2][4];
#pragma unroll
  for (int m = 0; m < 2; ++m)
#pragma unroll
    for (int kk = 0; kk < 4; ++kk)
      qf[m][kk] = *(const short8*)(qpack +
          ((((size_t)bh * 128 + (qrow_w >> 4) + m) * 4 + kk) * 64 + lane) * 8);

  short8 oneb;
#pragma unroll
  for (int e = 0; e < 8; ++e) oneb[e] = (short)0x3F80;

  const f32x4 zero = {0.f, 0.f, 0.f, 0.f};
  f32x4 o_acc[2][8];
  f32x4 l_acc[2];
#pragma unroll
  for (int m = 0; m < 2; ++m) {
    l_acc[m] = zero;
#pragma unroll
    for (int i = 0; i < 8; ++i) o_acc[m][i] = zero;
  }

  const int nt = (k_end - k_begin) >> 5;
  int ntv = ((qrow_w + 31 - k_begin) >> 5) + 1;
  if (ntv > nt) ntv = nt;

  auto loadK = [&](short8 (&kf)[2][4], int t) {
    const int kvb = (k_begin >> 4) + t * 2;
#pragma unroll
    for (int n = 0; n < 2; ++n)
#pragma unroll
      for (int kk = 0; kk < 4; ++kk)
        kf[n][kk] = *(const short8*)(kpack +
            ((((size_t)bh * 128 + kvb + n) * 4 + kk) * 64 + lane) * 8);
  };
  auto loadV = [&](short8 (&vb)[8], int t) {
    const int kvb32 = (k_begin >> 5) + t;
#pragma unroll
    for (int d8 = 0; d8 < 8; ++d8)
      vb[d8] = *(const short8*)(vpack +
          ((((size_t)bh * 64 + kvb32) * 8 + d8) * 64 + lane) * 8);
  };
  auto compute = [&](int t, short8 (&kf)[2][4], short8 (&vb)[8]) {
    const int kbase = k_begin + t * 32;
    f32x4 sa[2][2];
    sa[0][0] = zero; sa[0][1] = zero; sa[1][0] = zero; sa[1][1] = zero;
#pragma unroll
    for (int n = 0; n < 2; ++n)
#pragma unroll
      for (int kk = 0; kk < 4; ++kk) {
        sa[0][n] = MFMA16(qf[0][kk], kf[n][kk], sa[0][n], 0, 0, 0);
        sa[1][n] = MFMA16(qf[1][kk], kf[n][kk], sa[1][n], 0, 0, 0);
      }
    const bool need_mask = (kbase + 31 > qrow_w);
    float p[2][2][4];
#pragma unroll
    for (int m = 0; m < 2; ++m)
#pragma unroll
      for (int n = 0; n < 2; ++n)
#pragma unroll
        for (int r = 0; r < 4; ++r) {
          const float v = exp2f(sa[m][n][r] * SCALE2 - 24.f);
          bool msk = false;
          if (need_mask) {
            const int kc = kbase + n * 16 + l15;
            const int qr = qrow_w + m * 16 + (l4 << 2) + r;
            msk = (kc > qr);
          }
          p[m][n][r] = msk ? 0.f : v;
        }
#pragma unroll
    for (int m = 0; m < 2; ++m)
#pragma unroll
      for (int n = 0; n < 2; ++n)
#pragma unroll
        for (int r = 0; r < 4; ++r)
          P_lds[wave][m * 16 + (l4 << 2) + r][n * 16 + l15] = f2bf(p[m][n][r]);
    short8 pa[2];
#pragma unroll
    for (int m = 0; m < 2; ++m)
      pa[m] = *(const short8*)((const char*)&P_lds[wave][0][0] +
                               (m * 16 + l15) * 72 + (l4 << 4));
    l_acc[0] = MFMA16(pa[0], oneb, l_acc[0], 0, 0, 0);
    l_acc[1] = MFMA16(pa[1], oneb, l_acc[1], 0, 0, 0);
#pragma unroll
    for (int d8 = 0; d8 < 8; ++d8) {
      o_acc[0][d8] = MFMA16(pa[0], vb[d8], o_acc[0][d8], 0, 0, 0);
      o_acc[1][d8] = MFMA16(pa[1], vb[d8], o_acc[1][d8], 0, 0, 0);
    }
  };

  short8 kfA[2][4], vbA[8], kfB[2][4], vbB[8];
  loadK(kfA, 0);
  loadV(vbA, 0);
  for (int t = 0; t < ntv; t += 2) {
    if (t + 1 < ntv) { loadK(kfB, t + 1); loadV(vbB, t + 1); }
    compute(t, kfA, vbA);
    if (t + 1 < ntv) {
      if (t + 2 < ntv) { loadK(kfA, t + 2); loadV(vbA, t + 2); }
      compute(t + 1, kfB, vbB);
    }
  }

  if (g == 0) {
#pragma unroll
    for (int m = 0; m < 2; ++m)
#pragma unroll
      for (int d8 = 0; d8 < 8; ++d8)
#pragma unroll
        for (int r = 0; r < 4; ++r) {
          const int row = brow + qrow_w + m * 16 + (l4 << 2) + r;
          Oh[(size_t)row * 512 + h * 128 + d8 * 16 + l15] =
              f2bf(o_acc[m][d8][r] / l_acc[m][r]);
        }
  } else {
    const int slot = bh * 144 + jid;
    unsigned short* po = pO + (size_t)slot * 64 * 128;
#pragma unroll
    for (int m = 0; m < 2; ++m)
#pragma unroll
      for (int d8 = 0; d8 < 8; ++d8)
#pragma unroll
        for (int r = 0; r < 4; ++r) {
          const int row = wave * 32 + m * 16 + (l4 << 2) + r;
          po[row * 128 + d8 * 16 + l15] = f2bf(o_acc[m][d8][r]);
        }
    if (l15 == 0) {
#pragma unroll
      for (int m = 0; m < 2; ++m)
#pragma unroll
        for (int r = 0; r < 4; ++r) {
          const int row = wave * 32 + m * 16 + (l4 << 2) + r;
          pml[((size_t)slot * 64 + row) * 2 + 0] = 0.f;
          pml[((size_t)slot * 64 + row) * 2 + 1] = l_acc[m][r];
        }
    }
  }
}

// Combine partials for qt >= 4 (static max -> all weights 1).
__global__ __launch_bounds__(256)
void attn_combine(const unsigned short* __restrict__ pO,
                  const float* __restrict__ pml,
                  unsigned short* __restrict__ Oh) {
  const int bh = blockIdx.y;
  const int qt = 4 + blockIdx.x;
  const int g = qt >> 2;
  const int nch = g + 1;
  const int base = 2 * g * (g + 1) + (qt & 3) * (g + 1);
  const int slot0 = bh * 144 + base;
  const int brow = (bh >> 2) * 2048;
  const int h = bh & 3;
#pragma unroll
  for (int u = 0; u < 4; ++u) {
    const int unit = u * 256 + threadIdx.x;
    const int row = unit >> 4;
    const int c8 = (unit & 15) << 3;
    float M = -1e30f;
    for (int c = 0; c < nch; ++c)
      M = fmaxf(M, pml[((size_t)(slot0 + c) * 64 + row) * 2]);
    float L = 0.f;
    float acc[8] = {0.f, 0.f, 0.f, 0.f, 0.f, 0.f, 0.f, 0.f};
    for (int c = 0; c < nch; ++c) {
      const float mc = pml[((size_t)(slot0 + c) * 64 + row) * 2];
      const float lc = pml[((size_t)(slot0 + c) * 64 + row) * 2 + 1];
      const float w = exp2f(mc - M);
      L += w * lc;
      const short8 ov =
          *(const short8*)(pO + ((size_t)(slot0 + c) * 64 + row) * 128 + c8);
#pragma unroll
      for (int e = 0; e < 8; ++e) acc[e] += w * bf2f((unsigned short)ov[e]);
    }
    const float inv = 1.f / L;
    short8 o;
#pragma unroll
    for (int e = 0; e < 8; ++e) o[e] = (short)f2bf(acc[e] * inv);
    *(short8*)(Oh + (size_t)(brow + qt * 64 + row) * 512 + h * 128 + c8) = o;
  }
}

// ---------------------------------------------------------------------------
extern "C" void kernel_launch(void* const* d_in, const int* in_sizes, int n_in,
                              void* d_out, int out_size, void* d_ws, size_t ws_size,
                              hipStream_t stream) {
  const float* Q  = (const float*)d_in[0];
  const float* K_ = (const float*)d_in[1];
  const float* V  = (const float*)d_in[2];
  const float* Wq = (const float*)d_in[3];
  const float* Wk = (const float*)d_in[4];
  const float* Wv = (const float*)d_in[5];
  const float* Wo = (const float*)d_in[6];
  float* out = (float*)d_out;

  // ws layout (bytes), total 48824320 (identical to R12/R14):
  //   0         : Wt    3 x [512][2048] bf16
  //   6291456   : WoT   [2048][512] bf16
  //   8388608   : qpack (4.19 MB)
  //   12582912  : kpack (4.19 MB)
  //   16777216  : vpack (4.19 MB)
  //   20971520  : pC    2 slots x 12.58 MB split-K partials -> [20.97M,46.14M)
  //               Oh reuses [20.97M,25.17M) (pC slot0 q-region, dead after
  //               qkv_pack); pO reuses [25165824, 44040192) after vpack_k
  //               consumed the v slices.
  //   25165824  : pO   [1152][64][128] bf16
  //   48234496  : pml  [1152][64][2] f32
  char* ws = (char*)d_ws;
  unsigned short* Wt    = (unsigned short*)ws;
  unsigned short* WoT   = (unsigned short*)(ws + 6291456);
  unsigned short* qpack = (unsigned short*)(ws + 8388608);
  unsigned short* kpack = (unsigned short*)(ws + 12582912);
  unsigned short* vpack = (unsigned short*)(ws + 16777216);
  unsigned short* Oh    = (unsigned short*)(ws + 20971520);
  unsigned short* pC    = (unsigned short*)(ws + 20971520);
  unsigned short* pO    = (unsigned short*)(ws + 25165824);
  float*          pml   = (float*)(ws + 48234496);

  // fused weight prep (one launch)
  prep_all<<<1024, 256, 0, stream>>>(Wq, Wk, Wv, Wo, Wt, WoT);

  // q/k/v projections, split-K x2: 768 blocks
  gemm_bt<true, unsigned short, 2><<<768, 256, 0, stream>>>(
      Q, K_, V, Wt, pC, /*K=*/2048, /*N=*/512, /*sB=*/1048576, /*sC=*/2097152);
  // combine + fragment-pack q,k ; combine + pack v
  qkv_pack<<<1024, 256, 0, stream>>>(pC, qpack, kpack);
  vpack_k<<<dim3(64, 8), 256, 0, stream>>>(pC, vpack);

  // split-KV causal attention (packed operands, pipelined) + combine
  attn_split<<<1152, 128, 0, stream>>>(qpack, kpack, vpack, Oh, pO, pml);
  attn_combine<<<dim3(28, 8), 256, 0, stream>>>(pO, pml, Oh);

  // output projection: 512 blocks
  gemm_bt<false, float, 1><<<512, 256, 0, stream>>>(
      Oh, Oh, Oh, WoT, out, /*K=*/512, /*N=*/2048, /*sB=*/0, /*sC=*/0);
}

// Round 17
// 127.075 us; speedup vs baseline: 1.1947x; 1.0147x over previous
//
#include <hip/hip_runtime.h>
#include <hip/hip_bf16.h>

typedef __attribute__((ext_vector_type(8))) short short8;
typedef __attribute__((ext_vector_type(4))) float f32x4;

#define MFMA16 __builtin_amdgcn_mfma_f32_16x16x32_bf16

__device__ inline unsigned short f2bf(float f) {
  __hip_bfloat16 h = __float2bfloat16(f);
  unsigned short u;
  __builtin_memcpy(&u, &h, 2);
  return u;
}

__device__ inline float bf2f(unsigned short u) {
  unsigned int x = ((unsigned int)u) << 16;
  float f;
  __builtin_memcpy(&f, &x, 4);
  return f;
}

__device__ inline void storeC(unsigned short* p, float v) { *p = f2bf(v); }
__device__ inline void storeC(float* p, float v) { *p = v; }

__device__ inline void gload16(const void* g, void* l) {
  __builtin_amdgcn_global_load_lds(
      (const __attribute__((address_space(1))) unsigned int*)g,
      (__attribute__((address_space(3))) unsigned int*)l,
      16, 0, 0);
}

// ---------------------------------------------------------------------------
// Fused weight prep (one launch, 1024 blocks):
//   bid [0,256)    : wqsum  dst[n][d] = sum_g Wq[d][n+g*512]  (512x2048 out)
//   bid [256,512)  : Wk^T -> Wt+1048576   (2048x512 -> 512x2048)
//   bid [512,768)  : Wv^T -> Wt+2097152
//   bid [768,1024) : Wo^T -> WoT          (512x2048 -> 2048x512)
__global__ __launch_bounds__(256)
void prep_all(const float* __restrict__ Wq, const float* __restrict__ Wk,
              const float* __restrict__ Wv, const float* __restrict__ Wo,
              unsigned short* __restrict__ Wt, unsigned short* __restrict__ WoT) {
  __shared__ float t[64][65];
  const int bid = blockIdx.x;
  const int tid = threadIdx.x;
  if (bid < 256) {
    const int n0 = (bid & 7) * 64, d0 = (bid >> 3) * 64;
#pragma unroll
    for (int it = 0; it < 16; ++it) {
      const int idx = it * 256 + tid;
      const int dd = idx >> 6, nn = idx & 63;
      const float* p = Wq + (size_t)(d0 + dd) * 2048 + n0 + nn;
      t[dd][nn] = p[0] + p[512] + p[1024] + p[1536];
    }
    __syncthreads();
#pragma unroll
    for (int it = 0; it < 16; ++it) {
      const int idx = it * 256 + tid;
      const int nn = idx >> 6, dd = idx & 63;
      Wt[(size_t)(n0 + nn) * 2048 + d0 + dd] = f2bf(t[dd][nn]);
    }
    return;
  }
  const float* src;
  unsigned short* dst;
  int R, C, c0, r0;
  if (bid < 768) {
    const int b = bid - 256;
    const int z = b >> 8;              // 0: Wk, 1: Wv
    const int bb = b & 255;
    src = z ? Wv : Wk;
    dst = Wt + (z ? 2097152 : 1048576);
    R = 2048; C = 512;
    c0 = (bb & 7) * 64; r0 = (bb >> 3) * 64;
  } else {
    const int b = bid - 768;
    src = Wo; dst = WoT;
    R = 512; C = 2048;
    c0 = (b & 31) * 64; r0 = (b >> 5) * 64;
  }
#pragma unroll
  for (int it = 0; it < 16; ++it) {
    const int idx = it * 256 + tid;
    const int r = idx >> 6, c = idx & 63;
    t[r][c] = src[(size_t)(r0 + r) * C + c0 + c];
  }
  __syncthreads();
#pragma unroll
  for (int it = 0; it < 16; ++it) {
    const int idx = it * 256 + tid;
    const int rr = idx >> 6, cc = idx & 63;
    dst[(size_t)(c0 + rr) * R + r0 + cc] = f2bf(t[cc][rr]);
  }
}

// ---------------------------------------------------------------------------
// GEMM C[M,N] = A[M,K] * Bt[N,K]^T.  128x128 tile, BK=64, 4 waves, T2 swizzle,
// KS split-K, XCD swizzle, cross-barrier prefetch (stable since R8).
template <bool AF32, typename CT, int KS>
__global__ __launch_bounds__(256)
void gemm_bt(const void* A0, const void* A1, const void* A2,
             const unsigned short* __restrict__ Bt, CT* __restrict__ C,
             int K, int N, size_t sB, size_t sC) {
  __shared__ unsigned short As[AF32 ? 1 : 2][128 * 64];
  __shared__ unsigned short Bs[2][128 * 64];

  const int tid = threadIdx.x;
  const int lane = tid & 63;
  const int wv = tid >> 6;
  const int wm = (wv >> 1) << 6;
  const int wn = (wv & 1) << 6;
  const int l15 = lane & 15;
  const int l4 = lane >> 4;
  const int lsw = (l15 & 7) << 4;

  const int nwg = gridDim.x;
  const int bid = blockIdx.x;
  const int job = (bid & 7) * (nwg >> 3) + (bid >> 3);
  const int ntile = N >> 7;
  const int per_ks = nwg / KS;
  const int ks = (KS > 1) ? (job / per_ks) : 0;
  const int jj = job - ks * per_ks;
  const int z = jj / (32 * ntile);
  const int rem = jj - z * 32 * ntile;
  const int m0 = (rem / ntile) << 7;
  const int n0 = (rem % ntile) << 7;
  const int kbeg = ks * (K / KS);
  const int kend = kbeg + K / KS;

  const void* Az = (z == 0) ? A0 : (z == 1) ? A1 : A2;
  const unsigned short* Ab = (const unsigned short*)Az;
  const float* Af = (const float*)Az;
  const unsigned short* Bz = Bt + sB * (size_t)z;

  const f32x4 zero = {0.f, 0.f, 0.f, 0.f};
  f32x4 acc[4][4];
#pragma unroll
  for (int i = 0; i < 4; ++i)
#pragma unroll
    for (int j = 0; j < 4; ++j) acc[i][j] = zero;

  const int srow = tid >> 3;
  const int scol = (tid & 7) << 3;
  const int scolsw = scol ^ ((srow & 7) << 3);

  float4 ar[8];

  auto issueB = [&](int buf, int k0) {
#pragma unroll
    for (int s = 0; s < 4; ++s) {
      const unsigned short* bsrc =
          Bz + (size_t)(n0 + srow + s * 32) * K + k0 + scolsw;
      gload16(bsrc, (char*)&Bs[buf][0] + tid * 16 + s * 4096);
    }
  };
  auto issueA16 = [&](int buf, int k0) {
#pragma unroll
    for (int s = 0; s < 4; ++s) {
      const unsigned short* asrc =
          Ab + (size_t)(m0 + srow + s * 32) * K + k0 + scolsw;
      gload16(asrc, (char*)&As[buf][0] + tid * 16 + s * 4096);
    }
  };
  auto loadA = [&](int k0) {
#pragma unroll
    for (int s = 0; s < 4; ++s) {
      const float* asrc = Af + (size_t)(m0 + srow + s * 32) * K + k0 + scol;
      ar[2 * s] = *(const float4*)(asrc);
      ar[2 * s + 1] = *(const float4*)(asrc + 4);
    }
  };
  auto writeA = [&]() {
#pragma unroll
    for (int s = 0; s < 4; ++s) {
      short8 o;
      o[0] = (short)f2bf(ar[2 * s].x); o[1] = (short)f2bf(ar[2 * s].y);
      o[2] = (short)f2bf(ar[2 * s].z); o[3] = (short)f2bf(ar[2 * s].w);
      o[4] = (short)f2bf(ar[2 * s + 1].x); o[5] = (short)f2bf(ar[2 * s + 1].y);
      o[6] = (short)f2bf(ar[2 * s + 1].z); o[7] = (short)f2bf(ar[2 * s + 1].w);
      *(short8*)((char*)&As[0][0] + (srow + s * 32) * 128 + scolsw * 2) = o;
    }
  };

  if constexpr (AF32) loadA(kbeg); else issueA16(0, kbeg);
  issueB(0, kbeg);

  int cur = 0;
  for (int k0 = kbeg; k0 < kend; k0 += 64) {
    const bool more = (k0 + 64 < kend);
    asm volatile("s_waitcnt vmcnt(0)" ::: "memory");
    if constexpr (AF32) {
      writeA();
      if (more) { issueB(cur ^ 1, k0 + 64); loadA(k0 + 64); }
      asm volatile("s_waitcnt lgkmcnt(0)" ::: "memory");
    } else {
      if (more) { issueA16(cur ^ 1, k0 + 64); issueB(cur ^ 1, k0 + 64); }
    }
    __builtin_amdgcn_s_barrier();
    const unsigned short* as = AF32 ? &As[0][0] : &As[cur][0];
#pragma unroll
    for (int kk = 0; kk < 2; ++kk) {
      const int kb = (kk * 64 + (l4 << 4)) ^ lsw;
      short8 a[4], b[4];
#pragma unroll
      for (int i = 0; i < 4; ++i)
        a[i] = *(const short8*)((const char*)as + (wm + i * 16 + l15) * 128 + kb);
#pragma unroll
      for (int j = 0; j < 4; ++j)
        b[j] = *(const short8*)((const char*)&Bs[cur][0] +
                                (wn + j * 16 + l15) * 128 + kb);
#pragma unroll
      for (int i = 0; i < 4; ++i)
#pragma unroll
        for (int j = 0; j < 4; ++j)
          acc[i][j] = MFMA16(a[i], b[j], acc[i][j], 0, 0, 0);
    }
    __builtin_amdgcn_s_barrier();
    cur ^= 1;
  }

  CT* Cz = C + sC * (size_t)(ks * 3 + z);
#pragma unroll
  for (int i = 0; i < 4; ++i) {
    const int row0 = m0 + wm + i * 16 + (l4 << 2);
#pragma unroll
    for (int j = 0; j < 4; ++j) {
      const int col = n0 + wn + j * 16 + l15;
#pragma unroll
      for (int r = 0; r < 4; ++r)
        storeC(&Cz[(size_t)(row0 + r) * N + col], acc[i][j][r]);
    }
  }
}

// ---------------------------------------------------------------------------
// Combine split-K partials for q,k AND emit fragment-major packed layouts:
//   qpack/kpack[bh][blk16][kk][lane64][e8]:
//     value = X[(bh>>2)*2048 + blk*16 + (lane&15)][(bh&3)*128 + kk*32 +
//              (lane>>4)*8 + e]
__global__ __launch_bounds__(256)
void qkv_pack(const unsigned short* __restrict__ pC,
              unsigned short* __restrict__ qpack,
              unsigned short* __restrict__ kpack) {
  const size_t SLOTE = 6291456;  // elems per ks slot
  const int idx = blockIdx.x * 256 + threadIdx.x;  // [bh][qb][kk][lane]
  const int lane = idx & 63;
  const int kk = (idx >> 6) & 3;
  const int qb = (idx >> 8) & 127;
  const int bh = idx >> 15;
  const int row = (bh >> 2) * 2048 + qb * 16 + (lane & 15);
  const int col = (bh & 3) * 128 + kk * 32 + (lane >> 4) * 8;
  const size_t off = (size_t)row * 512 + col;
  {
    const short8 a = *(const short8*)(pC + off);
    const short8 b = *(const short8*)(pC + SLOTE + off);
    short8 o;
#pragma unroll
    for (int e = 0; e < 8; ++e)
      o[e] = (short)f2bf(bf2f((unsigned short)a[e]) + bf2f((unsigned short)b[e]));
    *(short8*)(qpack + (size_t)idx * 8) = o;
  }
  {
    const short8 a = *(const short8*)(pC + 2097152 + off);
    const short8 b = *(const short8*)(pC + SLOTE + 2097152 + off);
    short8 o;
#pragma unroll
    for (int e = 0; e < 8; ++e)
      o[e] = (short)f2bf(bf2f((unsigned short)a[e]) + bf2f((unsigned short)b[e]));
    *(short8*)(kpack + (size_t)idx * 8) = o;
  }
}

// Combine split-K V partials and emit packed PV B-operand layout:
//   vpack[bh][kvb32][d8][lane64][e8] = V[b][kvb32*32 + (lane>>4)*8 + e]
//                                       [h*128 + d8*16 + (lane&15)]
__global__ __launch_bounds__(256)
void vpack_k(const unsigned short* __restrict__ pC,
             unsigned short* __restrict__ vpack) {
  __shared__ unsigned short t[32][132];
  const int kvb = blockIdx.x;
  const int bh = blockIdx.y;
  const int brow = (bh >> 2) * 2048;
  const int h = bh & 3;
  const int tid = threadIdx.x;
  const unsigned short* v0 = pC + 4194304;            // ks=0, z=2 slice
  const unsigned short* v1 = pC + 6291456 + 4194304;  // ks=1, z=2 slice
#pragma unroll
  for (int it = 0; it < 2; ++it) {
    const int idx = it * 256 + tid;
    const int r = idx >> 4;
    const int c8 = (idx & 15) << 3;
    const size_t off = (size_t)(brow + kvb * 32 + r) * 512 + h * 128 + c8;
    const short8 xa = *(const short8*)(v0 + off);
    const short8 xb = *(const short8*)(v1 + off);
    short8 o;
#pragma unroll
    for (int e = 0; e < 8; ++e)
      o[e] = (short)f2bf(bf2f((unsigned short)xa[e]) + bf2f((unsigned short)xb[e]));
    *(short8*)&t[r][c8] = o;
  }
  __syncthreads();
#pragma unroll
  for (int it = 0; it < 2; ++it) {
    const int idx = it * 256 + tid;
    const int d8 = idx >> 6;
    const int lane = idx & 63;
    const int l15 = lane & 15;
    const int l4 = lane >> 4;
    short8 o;
#pragma unroll
    for (int e = 0; e < 8; ++e) o[e] = (short)t[l4 * 8 + e][d8 * 16 + l15];
    *(short8*)(vpack + ((((size_t)bh * 64 + kvb) * 8 + d8) * 64 + lane) * 8) = o;
  }
}

// ---------------------------------------------------------------------------
// Split-KV flash attention v5: packed operands (1KB contiguous wave-loads),
// tile-level prefetch (unroll-2, named reg sets), static-max softmax
// p = exp2(s*log2e/sqrt(128) - 24), barrier-free, XCD-bh affinity,
// longest-job-first, l row-sum via MFMA(pa, ones).
__global__ __launch_bounds__(128, 1)
void attn_split(const unsigned short* __restrict__ qpack,
                const unsigned short* __restrict__ kpack,
                const unsigned short* __restrict__ vpack,
                unsigned short* __restrict__ Oh,
                unsigned short* __restrict__ pO,
                float* __restrict__ pml) {
  __shared__ unsigned short P_lds[2][32][36];
  const int tid = threadIdx.x;
  const int lane = tid & 63;
  const int wave = tid >> 6;
  const int l15 = lane & 15;
  const int l4 = lane >> 4;
  const int bh = blockIdx.x & 7;
  const int jid = 143 - (int)(blockIdx.x >> 3);
  const int brow = (bh >> 2) * 2048;
  const int h = bh & 3;

  int j = jid, g = 0;
  while (j >= 2 * (g + 1) * (g + 2)) ++g;
  const int rem = j - 2 * g * (g + 1);
  const int r_ = rem / (g + 1);
  const int c_ = rem - r_ * (g + 1);
  const int qt = 4 * g + r_;
  const int k_begin = c_ << 8;
  const int k_end = (c_ == g) ? (qt + 1) * 64 : ((c_ + 1) << 8);
  const int qrow_w = qt * 64 + wave * 32;
  const float SCALE2 = 0.127517424f;  // log2(e)/sqrt(128)

  short8 qf[2][4];
#pragma unroll
  for (int m = 0; m < 2; ++m)
#pragma unroll
    for (int kk = 0; kk < 4; ++kk)
      qf[m][kk] = *(const short8*)(qpack +
          ((((size_t)bh * 128 + (qrow_w >> 4) + m) * 4 + kk) * 64 + lane) * 8);

  short8 oneb;
#pragma unroll
  for (int e = 0; e < 8; ++e) oneb[e] = (short)0x3F80;

  const f32x4 zero = {0.f, 0.f, 0.f, 0.f};
  f32x4 o_acc[2][8];
  f32x4 l_acc[2];
#pragma unroll
  for (int m = 0; m < 2; ++m) {
    l_acc[m] = zero;
#pragma unroll
    for (int i = 0; i < 8; ++i) o_acc[m][i] = zero;
  }

  const int nt = (k_end - k_begin) >> 5;
  int ntv = ((qrow_w + 31 - k_begin) >> 5) + 1;
  if (ntv > nt) ntv = nt;

  auto loadK = [&](short8 (&kf)[2][4], int t) {
    const int kvb = (k_begin >> 4) + t * 2;
#pragma unroll
    for (int n = 0; n < 2; ++n)
#pragma unroll
      for (int kk = 0; kk < 4; ++kk)
        kf[n][kk] = *(const short8*)(kpack +
            ((((size_t)bh * 128 + kvb + n) * 4 + kk) * 64 + lane) * 8);
  };
  auto loadV = [&](short8 (&vb)[8], int t) {
    const int kvb32 = (k_begin >> 5) + t;
#pragma unroll
    for (int d8 = 0; d8 < 8; ++d8)
      vb[d8] = *(const short8*)(vpack +
          ((((size_t)bh * 64 + kvb32) * 8 + d8) * 64 + lane) * 8);
  };
  auto compute = [&](int t, short8 (&kf)[2][4], short8 (&vb)[8]) {
    const int kbase = k_begin + t * 32;
    f32x4 sa[2][2];
    sa[0][0] = zero; sa[0][1] = zero; sa[1][0] = zero; sa[1][1] = zero;
#pragma unroll
    for (int n = 0; n < 2; ++n)
#pragma unroll
      for (int kk = 0; kk < 4; ++kk) {
        sa[0][n] = MFMA16(qf[0][kk], kf[n][kk], sa[0][n], 0, 0, 0);
        sa[1][n] = MFMA16(qf[1][kk], kf[n][kk], sa[1][n], 0, 0, 0);
      }
    const bool need_mask = (kbase + 31 > qrow_w);
    float p[2][2][4];
#pragma unroll
    for (int m = 0; m < 2; ++m)
#pragma unroll
      for (int n = 0; n < 2; ++n)
#pragma unroll
        for (int r = 0; r < 4; ++r) {
          const float v = exp2f(sa[m][n][r] * SCALE2 - 24.f);
          bool msk = false;
          if (need_mask) {
            const int kc = kbase + n * 16 + l15;
            const int qr = qrow_w + m * 16 + (l4 << 2) + r;
            msk = (kc > qr);
          }
          p[m][n][r] = msk ? 0.f : v;
        }
#pragma unroll
    for (int m = 0; m < 2; ++m)
#pragma unroll
      for (int n = 0; n < 2; ++n)
#pragma unroll
        for (int r = 0; r < 4; ++r)
          P_lds[wave][m * 16 + (l4 << 2) + r][n * 16 + l15] = f2bf(p[m][n][r]);
    short8 pa[2];
#pragma unroll
    for (int m = 0; m < 2; ++m)
      pa[m] = *(const short8*)((const char*)&P_lds[wave][0][0] +
                               (m * 16 + l15) * 72 + (l4 << 4));
    l_acc[0] = MFMA16(pa[0], oneb, l_acc[0], 0, 0, 0);
    l_acc[1] = MFMA16(pa[1], oneb, l_acc[1], 0, 0, 0);
#pragma unroll
    for (int d8 = 0; d8 < 8; ++d8) {
      o_acc[0][d8] = MFMA16(pa[0], vb[d8], o_acc[0][d8], 0, 0, 0);
      o_acc[1][d8] = MFMA16(pa[1], vb[d8], o_acc[1][d8], 0, 0, 0);
    }
  };

  short8 kfA[2][4], vbA[8], kfB[2][4], vbB[8];
  loadK(kfA, 0);
  loadV(vbA, 0);
  for (int t = 0; t < ntv; t += 2) {
    if (t + 1 < ntv) { loadK(kfB, t + 1); loadV(vbB, t + 1); }
    compute(t, kfA, vbA);
    if (t + 1 < ntv) {
      if (t + 2 < ntv) { loadK(kfA, t + 2); loadV(vbA, t + 2); }
      compute(t + 1, kfB, vbB);
    }
  }

  if (g == 0) {
#pragma unroll
    for (int m = 0; m < 2; ++m)
#pragma unroll
      for (int d8 = 0; d8 < 8; ++d8)
#pragma unroll
        for (int r = 0; r < 4; ++r) {
          const int row = brow + qrow_w + m * 16 + (l4 << 2) + r;
          Oh[(size_t)row * 512 + h * 128 + d8 * 16 + l15] =
              f2bf(o_acc[m][d8][r] / l_acc[m][r]);
        }
  } else {
    const int slot = bh * 144 + jid;
    unsigned short* po = pO + (size_t)slot * 64 * 128;
#pragma unroll
    for (int m = 0; m < 2; ++m)
#pragma unroll
      for (int d8 = 0; d8 < 8; ++d8)
#pragma unroll
        for (int r = 0; r < 4; ++r) {
          const int row = wave * 32 + m * 16 + (l4 << 2) + r;
          po[row * 128 + d8 * 16 + l15] = f2bf(o_acc[m][d8][r]);
        }
    if (l15 == 0) {
#pragma unroll
      for (int m = 0; m < 2; ++m)
#pragma unroll
        for (int r = 0; r < 4; ++r) {
          const int row = wave * 32 + m * 16 + (l4 << 2) + r;
          pml[((size_t)slot * 64 + row) * 2 + 0] = 0.f;
          pml[((size_t)slot * 64 + row) * 2 + 1] = l_acc[m][r];
        }
    }
  }
}

// Combine partials for qt >= 4 (static max -> all weights 1).
__global__ __launch_bounds__(256)
void attn_combine(const unsigned short* __restrict__ pO,
                  const float* __restrict__ pml,
                  unsigned short* __restrict__ Oh) {
  const int bh = blockIdx.y;
  const int qt = 4 + blockIdx.x;
  const int g = qt >> 2;
  const int nch = g + 1;
  const int base = 2 * g * (g + 1) + (qt & 3) * (g + 1);
  const int slot0 = bh * 144 + base;
  const int brow = (bh >> 2) * 2048;
  const int h = bh & 3;
#pragma unroll
  for (int u = 0; u < 4; ++u) {
    const int unit = u * 256 + threadIdx.x;
    const int row = unit >> 4;
    const int c8 = (unit & 15) << 3;
    float M = -1e30f;
    for (int c = 0; c < nch; ++c)
      M = fmaxf(M, pml[((size_t)(slot0 + c) * 64 + row) * 2]);
    float L = 0.f;
    float acc[8] = {0.f, 0.f, 0.f, 0.f, 0.f, 0.f, 0.f, 0.f};
    for (int c = 0; c < nch; ++c) {
      const float mc = pml[((size_t)(slot0 + c) * 64 + row) * 2];
      const float lc = pml[((size_t)(slot0 + c) * 64 + row) * 2 + 1];
      const float w = exp2f(mc - M);
      L += w * lc;
      const short8 ov =
          *(const short8*)(pO + ((size_t)(slot0 + c) * 64 + row) * 128 + c8);
#pragma unroll
      for (int e = 0; e < 8; ++e) acc[e] += w * bf2f((unsigned short)ov[e]);
    }
    const float inv = 1.f / L;
    short8 o;
#pragma unroll
    for (int e = 0; e < 8; ++e) o[e] = (short)f2bf(acc[e] * inv);
    *(short8*)(Oh + (size_t)(brow + qt * 64 + row) * 512 + h * 128 + c8) = o;
  }
}

// ---------------------------------------------------------------------------
extern "C" void kernel_launch(void* const* d_in, const int* in_sizes, int n_in,
                              void* d_out, int out_size, void* d_ws, size_t ws_size,
                              hipStream_t stream) {
  const float* Q  = (const float*)d_in[0];
  const float* K_ = (const float*)d_in[1];
  const float* V  = (const float*)d_in[2];
  const float* Wq = (const float*)d_in[3];
  const float* Wk = (const float*)d_in[4];
  const float* Wv = (const float*)d_in[5];
  const float* Wo = (const float*)d_in[6];
  float* out = (float*)d_out;

  // ws layout (bytes), total 48824320:
  //   0         : Wt    3 x [512][2048] bf16
  //   6291456   : WoT   [2048][512] bf16
  //   8388608   : qpack (4.19 MB)
  //   12582912  : kpack (4.19 MB)
  //   16777216  : vpack (4.19 MB)
  //   20971520  : pC    2 slots x 12.58 MB split-K partials -> [20.97M,46.14M)
  //               Oh reuses [20.97M,25.17M) (pC slot0 q-region, dead after
  //               qkv_pack); pO reuses [25165824, 44040192) after vpack_k
  //               consumed the v slices.
  //   25165824  : pO   [1152][64][128] bf16
  //   48234496  : pml  [1152][64][2] f32
  char* ws = (char*)d_ws;
  unsigned short* Wt    = (unsigned short*)ws;
  unsigned short* WoT   = (unsigned short*)(ws + 6291456);
  unsigned short* qpack = (unsigned short*)(ws + 8388608);
  unsigned short* kpack = (unsigned short*)(ws + 12582912);
  unsigned short* vpack = (unsigned short*)(ws + 16777216);
  unsigned short* Oh    = (unsigned short*)(ws + 20971520);
  unsigned short* pC    = (unsigned short*)(ws + 20971520);
  unsigned short* pO    = (unsigned short*)(ws + 25165824);
  float*          pml   = (float*)(ws + 48234496);

  // fused weight prep (one launch)
  prep_all<<<1024, 256, 0, stream>>>(Wq, Wk, Wv, Wo, Wt, WoT);

  // q/k/v projections, split-K x2: 768 blocks
  gemm_bt<true, unsigned short, 2><<<768, 256, 0, stream>>>(
      Q, K_, V, Wt, pC, /*K=*/2048, /*N=*/512, /*sB=*/1048576, /*sC=*/2097152);
  // combine + fragment-pack q,k ; combine + pack v
  qkv_pack<<<1024, 256, 0, stream>>>(pC, qpack, kpack);
  vpack_k<<<dim3(64, 8), 256, 0, stream>>>(pC, vpack);

  // split-KV causal attention (packed operands, pipelined) + combine
  attn_split<<<1152, 128, 0, stream>>>(qpack, kpack, vpack, Oh, pO, pml);
  attn_combine<<<dim3(28, 8), 256, 0, stream>>>(pO, pml, Oh);

  // output projection: 512 blocks
  gemm_bt<false, float, 1><<<512, 256, 0, stream>>>(
      Oh, Oh, Oh, WoT, out, /*K=*/512, /*N=*/2048, /*sB=*/0, /*sC=*/0);
}